// Round 1
// baseline (537.519 us; speedup 1.0000x reference)
//
#include <hip/hip_runtime.h>

// Spiking LIF forward scan.
// x: (B=128, C=512, T=1024) fp32, t contiguous. beta scalar, Vth per channel.
// One thread per (b,c) row; sequential recurrence over t.
// Memory-bound: 256 MB in + 256 MB out -> ~81 us floor at 6.3 TB/s.

#define LIF_B 128
#define LIF_C 512
#define LIF_T 1024

#define CHUNK 16               // time steps per chunk = 64 B = one cache line
#define NCH   (LIF_T / CHUNK)  // 64 chunks

__global__ __launch_bounds__(256) void lif_fwd(
    const float* __restrict__ x,
    const float* __restrict__ beta_p,
    const float* __restrict__ vth_p,
    float* __restrict__ out)
{
    const int bc = blockIdx.x * 256 + threadIdx.x;   // (b*C + c), 0..65535
    const float beta = beta_p[0];
    const float vth  = vth_p[bc & (LIF_C - 1)];      // C = 512 (pow2)

    const float4* __restrict__ xv = (const float4*)(x   + (size_t)bc * LIF_T);
    float4*       __restrict__ ov = (float4*)      (out + (size_t)bc * LIF_T);

    // Double-buffered prefetch, 2 chunks (8 float4 loads) deep.
    float4 b0[4], b1[4];
#pragma unroll
    for (int j = 0; j < 4; ++j) b0[j] = xv[j];
#pragma unroll
    for (int j = 0; j < 4; ++j) b1[j] = xv[4 + j];

    float mem = 0.0f, spk = 0.0f;

    auto do_chunk = [&](float4 (&cb)[4], int ch) {
        // Unpack current chunk to scalars (forces waitcnt on the 2-back loads,
        // frees cb registers for the next prefetch).
        float v[CHUNK];
#pragma unroll
        for (int j = 0; j < 4; ++j) {
            v[4 * j + 0] = cb[j].x;
            v[4 * j + 1] = cb[j].y;
            v[4 * j + 2] = cb[j].z;
            v[4 * j + 3] = cb[j].w;
        }
        // Prefetch chunk ch+2 into the buffer we just drained.
        const int pf = ch + 2;
        if (pf < NCH) {
#pragma unroll
            for (int j = 0; j < 4; ++j) cb[j] = xv[pf * 4 + j];
        }
        // The recurrence. Bit-exact fp32 op order vs numpy reference:
        //   rst = spk*Vth; mem = ((mem*beta) + x) - rst; spk = (mem - Vth) > 0.
        // __f*_rn intrinsics block -ffp-contract FMA fusion: a 1-ulp drift can
        // flip a spike (output error 1.0 > 2e-2 threshold).
        float o[CHUNK];
#pragma unroll
        for (int k = 0; k < CHUNK; ++k) {
            float rst = __fmul_rn(spk, vth);
            mem = __fsub_rn(__fadd_rn(__fmul_rn(mem, beta), v[k]), rst);
            spk = (__fsub_rn(mem, vth) > 0.0f) ? 1.0f : 0.0f;
            o[k] = spk;
        }
        // Store 64 B of spikes.
#pragma unroll
        for (int j = 0; j < 4; ++j) {
            float4 w;
            w.x = o[4 * j + 0];
            w.y = o[4 * j + 1];
            w.z = o[4 * j + 2];
            w.w = o[4 * j + 3];
            ov[ch * 4 + j] = w;
        }
    };

    // Manual unroll-by-2 keeps buffer indices static (no scratch spill from
    // dynamic indexing into b0/b1).
    for (int ch = 0; ch < NCH; ch += 2) {
        do_chunk(b0, ch);
        do_chunk(b1, ch + 1);
    }
}

extern "C" void kernel_launch(void* const* d_in, const int* in_sizes, int n_in,
                              void* d_out, int out_size, void* d_ws, size_t ws_size,
                              hipStream_t stream) {
    const float* x    = (const float*)d_in[0];  // (B, C, T) fp32
    const float* beta = (const float*)d_in[1];  // scalar
    const float* vth  = (const float*)d_in[2];  // (C,) fp32
    float* out = (float*)d_out;                 // (B, C, T) fp32

    dim3 grid((LIF_B * LIF_C) / 256);           // 256 blocks of 256 threads
    lif_fwd<<<grid, 256, 0, stream>>>(x, beta, vth, out);
}

// Round 2
// 523.927 us; speedup vs baseline: 1.0259x; 1.0259x over previous
//
#include <hip/hip_runtime.h>

// Spiking LIF forward scan, LDS-staged for fully coalesced global access.
//
// x: (B=128, C=512, T=1024) fp32, t contiguous. beta scalar, Vth per channel.
// Recurrence per (b,c) row is strictly sequential in t (Heaviside spike);
// parallelism = B*C = 65536 rows.
//
// Round-1 lesson: per-thread row walks make every VMEM instruction scatter 64
// requests on a 4 KB power-of-two stride -> 2.45 TB/s plateau + 1.6x write
// amplification (partial-line evictions). Fix: stage 64-row x 64-step tiles
// through LDS; all global loads/stores are 256 B-contiguous per 16-lane group.
//
// One wave (64 threads) per block, 64 rows per block, no barriers needed
// (wave-internal LDS ordering is in-order). Double-buffered LDS: 2 x 16 KB
// = 32 KB/block -> 4 blocks/CU (128 KB of 160 KB).
//
// LDS swizzle (4-float group granularity, preserves b128 alignment):
//   idx(row, t) = row*64 + ((t>>2) ^ (row & 15))*4 + (t & 3)
// - load/store phases: lane i handles (row = 4j + (i>>4), group = i & 15):
//   16 slots permuted within each row -> 8 words/bank (balanced floor).
// - compute phase: lane = row reads group g at slot g^(row&15): 16 slots x 4
//   lanes -> 8 words/bank (balanced floor). No serializing conflicts.

#define LIF_BC 65536
#define LIF_T  1024
#define TT     64            // time-steps per tile
#define NT     (LIF_T / TT)  // 16 tiles
#define ROWS   64            // rows per block == wave size

__global__ __launch_bounds__(64) void lif_fwd(
    const float* __restrict__ x,
    const float* __restrict__ beta_p,
    const float* __restrict__ vth_p,
    float* __restrict__ out)
{
    __shared__ float lds[2][ROWS * TT];

    const int lane = threadIdx.x;        // 0..63
    const int r0   = blockIdx.x * ROWS;  // first (b*C+c) row of this block

    const float beta = beta_p[0];
    const float vth  = vth_p[(r0 + lane) & 511];  // C = 512 (pow2)

    // load/store phase mapping: lane -> (row quad offset, 4-float group)
    const int l_row4 = lane >> 4;  // 0..3
    const int l_t    = lane & 15;  // group index within row

    float4 pf[16];  // register prefetch buffer: one full tile (64 VGPRs)

    // Issue 16 coalesced global loads for tile `tile` (each: 4 rows x 256 B).
    auto issue_loads = [&](int tile) {
#pragma unroll
        for (int j = 0; j < 16; ++j) {
            const int row = 4 * j + l_row4;
            pf[j] = *(const float4*)&x[(size_t)(r0 + row) * LIF_T
                                       + (size_t)tile * TT + l_t * 4];
        }
    };

    // Drain prefetch regs into an LDS buffer (swizzled, b128 writes).
    auto write_lds = [&](float* buf) {
#pragma unroll
        for (int j = 0; j < 16; ++j) {
            const int row  = 4 * j + l_row4;
            const int slot = l_t ^ (row & 15);
            *(float4*)&buf[row * TT + slot * 4] = pf[j];
        }
    };

    float mem = 0.0f, spk = 0.0f;

    // Run 64 recurrence steps for this lane's row; spikes overwrite x in place.
    // Bit-exact fp32 op order vs the numpy reference:
    //   rst = spk*Vth; mem = ((mem*beta) + x) - rst; spk = (mem - Vth) > 0.
    // __f*_rn blocks -ffp-contract FMA fusion (1-ulp drift flips a spike).
    auto compute = [&](float* buf) {
        const int rbase = lane * TT;
        const int sw    = lane & 15;
#pragma unroll
        for (int g = 0; g < 16; ++g) {
            float4 v = *(float4*)&buf[rbase + (g ^ sw) * 4];
            float o0, o1, o2, o3;
            {
                float rst = __fmul_rn(spk, vth);
                mem = __fsub_rn(__fadd_rn(__fmul_rn(mem, beta), v.x), rst);
                spk = (__fsub_rn(mem, vth) > 0.0f) ? 1.0f : 0.0f;
                o0 = spk;
            }
            {
                float rst = __fmul_rn(spk, vth);
                mem = __fsub_rn(__fadd_rn(__fmul_rn(mem, beta), v.y), rst);
                spk = (__fsub_rn(mem, vth) > 0.0f) ? 1.0f : 0.0f;
                o1 = spk;
            }
            {
                float rst = __fmul_rn(spk, vth);
                mem = __fsub_rn(__fadd_rn(__fmul_rn(mem, beta), v.z), rst);
                spk = (__fsub_rn(mem, vth) > 0.0f) ? 1.0f : 0.0f;
                o2 = spk;
            }
            {
                float rst = __fmul_rn(spk, vth);
                mem = __fsub_rn(__fadd_rn(__fmul_rn(mem, beta), v.w), rst);
                spk = (__fsub_rn(mem, vth) > 0.0f) ? 1.0f : 0.0f;
                o3 = spk;
            }
            v.x = o0; v.y = o1; v.z = o2; v.w = o3;
            *(float4*)&buf[rbase + (g ^ sw) * 4] = v;
        }
    };

    // Gather spikes from LDS (swizzled) and store coalesced to global.
    auto store_tile = [&](const float* buf, int tile) {
#pragma unroll
        for (int j = 0; j < 16; ++j) {
            const int row  = 4 * j + l_row4;
            const int slot = l_t ^ (row & 15);
            float4 s = *(const float4*)&buf[row * TT + slot * 4];
            *(float4*)&out[(size_t)(r0 + row) * LIF_T
                           + (size_t)tile * TT + l_t * 4] = s;
        }
    };

    // ---- software pipeline ----
    issue_loads(0);
    write_lds(lds[0]);   // waits vmcnt for tile 0
    issue_loads(1);      // tile 1 in flight across tile 0's compute

    for (int k = 0; k < NT; ++k) {
        float* cur = lds[k & 1];
        compute(cur);                                  // tile k (spikes in place)
        if (k + 1 < NT) write_lds(lds[(k + 1) & 1]);   // drain tile k+1 regs
        if (k + 2 < NT) issue_loads(k + 2);            // refill prefetch regs
        store_tile(cur, k);                            // coalesced spike store
    }
}

extern "C" void kernel_launch(void* const* d_in, const int* in_sizes, int n_in,
                              void* d_out, int out_size, void* d_ws, size_t ws_size,
                              hipStream_t stream) {
    const float* x    = (const float*)d_in[0];  // (B, C, T) fp32
    const float* beta = (const float*)d_in[1];  // scalar
    const float* vth  = (const float*)d_in[2];  // (C,) fp32
    float* out = (float*)d_out;                 // (B, C, T) fp32

    dim3 grid(LIF_BC / ROWS);                   // 1024 one-wave blocks
    lif_fwd<<<grid, 64, 0, stream>>>(x, beta, vth, out);
}

// Round 3
// 475.126 us; speedup vs baseline: 1.1313x; 1.1027x over previous
//
#include <hip/hip_runtime.h>

// Spiking LIF forward scan, LDS-staged + fully non-temporal global access.
//
// x: (B=128, C=512, T=1024) fp32, t contiguous. beta scalar, Vth per channel.
// Recurrence per (b,c) row is strictly sequential in t (Heaviside spike);
// parallelism = B*C = 65536 rows = 1024 waves = 4 waves/CU (structural).
//
// Round-2 lesson: stores/loads were coalesced (256 B segments) yet WRITE_SIZE
// was 2x ideal. Diagnosis: the harness's pre-launch x-restore + 0xAA poison
// leave ~256 MB of dirty lines in the Infinity Cache; our allocating accesses
// evict them inside our dispatch window (parasitic write-backs at full HBM
// cost). Fix: nt loads/stores (no allocation, evict-first on hit) so dirty
// harness lines stay cached and get overwritten in-place by the next restore.
//
// One wave (64 threads) per block, 64 rows/block. Double-buffered LDS tiles
// (2 x 16 KB) + TWO register prefetch buffers -> 32 KB of global loads in
// flight per wave during compute.
//
// LDS swizzle (4-float groups, preserves b128):
//   idx(row, t) = row*64 + ((t>>2) ^ (row & 15))*4 + (t & 3)
// Both phases hit the 8-words/bank balanced floor; round-2 measured
// SQ_LDS_BANK_CONFLICT = 0.

#define LIF_BC 65536
#define LIF_T  1024
#define TT     64            // time-steps per tile
#define NT     (LIF_T / TT)  // 16 tiles
#define ROWS   64            // rows per block == wave size

using fvec4 = __attribute__((ext_vector_type(4))) float;

__global__ __launch_bounds__(64) void lif_fwd(
    const float* __restrict__ x,
    const float* __restrict__ beta_p,
    const float* __restrict__ vth_p,
    float* __restrict__ out)
{
    __shared__ float lds0[ROWS * TT];
    __shared__ float lds1[ROWS * TT];

    const int lane = threadIdx.x;        // 0..63
    const int r0   = blockIdx.x * ROWS;  // first (b*C+c) row of this block

    const float beta = beta_p[0];
    const float vth  = vth_p[(r0 + lane) & 511];  // C = 512 (pow2)

    // load/store phase mapping: lane -> (row quad offset, 4-float group)
    const int l_row4 = lane >> 4;  // 0..3
    const int l_t    = lane & 15;  // group index within row

    fvec4 pf0[16], pf1[16];  // two tile-deep prefetch buffers (128 VGPRs)

    // 16 nt loads for tile `tile` (each instr: 4 rows x 256 B contiguous).
    auto issue_loads = [&](fvec4 (&pf)[16], int tile) {
#pragma unroll
        for (int j = 0; j < 16; ++j) {
            const int row = 4 * j + l_row4;
            pf[j] = __builtin_nontemporal_load(
                (const fvec4*)&x[(size_t)(r0 + row) * LIF_T
                                 + (size_t)tile * TT + l_t * 4]);
        }
    };

    // Drain a prefetch buffer into an LDS tile (swizzled b128 writes).
    auto write_lds = [&](float* buf, fvec4 (&pf)[16]) {
#pragma unroll
        for (int j = 0; j < 16; ++j) {
            const int row  = 4 * j + l_row4;
            const int slot = l_t ^ (row & 15);
            *(fvec4*)&buf[row * TT + slot * 4] = pf[j];
        }
    };

    float mem = 0.0f, spk = 0.0f;

    // 64 recurrence steps for this lane's row; spikes overwrite x in place.
    // Bit-exact fp32 op order vs the numpy reference:
    //   rst = spk*Vth; mem = ((mem*beta) + x) - rst; spk = (mem - Vth) > 0.
    // __f*_rn blocks -ffp-contract FMA fusion (1-ulp drift flips a spike).
    auto compute = [&](float* buf) {
        const int rbase = lane * TT;
        const int sw    = lane & 15;
#pragma unroll
        for (int g = 0; g < 16; ++g) {
            fvec4 v = *(fvec4*)&buf[rbase + (g ^ sw) * 4];
#pragma unroll
            for (int e = 0; e < 4; ++e) {
                float rst = __fmul_rn(spk, vth);
                mem = __fsub_rn(__fadd_rn(__fmul_rn(mem, beta), v[e]), rst);
                spk = (__fsub_rn(mem, vth) > 0.0f) ? 1.0f : 0.0f;
                v[e] = spk;
            }
            *(fvec4*)&buf[rbase + (g ^ sw) * 4] = v;
        }
    };

    // Gather spikes from LDS and stream (nt) to global, coalesced.
    auto store_tile = [&](const float* buf, int tile) {
#pragma unroll
        for (int j = 0; j < 16; ++j) {
            const int row  = 4 * j + l_row4;
            const int slot = l_t ^ (row & 15);
            fvec4 s = *(const fvec4*)&buf[row * TT + slot * 4];
            __builtin_nontemporal_store(
                s, (fvec4*)&out[(size_t)(r0 + row) * LIF_T
                                + (size_t)tile * TT + l_t * 4]);
        }
    };

    // ---- software pipeline: 2 tiles of loads in flight during compute ----
    issue_loads(pf0, 0);
    issue_loads(pf1, 1);
    write_lds(lds0, pf0);   // waits tile-0 loads (vmcnt issue-ordered)
    issue_loads(pf0, 2);

    for (int k = 0; k < NT; k += 2) {
        // even tile k (lds0 / pf0 side)
        compute(lds0);
        store_tile(lds0, k);                            // nt stores, fire & forget
        write_lds(lds1, pf1);                           // tile k+1 regs -> LDS
        if (k + 3 < NT) issue_loads(pf1, k + 3);
        // odd tile k+1 (lds1 / pf1 side)
        compute(lds1);
        store_tile(lds1, k + 1);
        if (k + 2 < NT) write_lds(lds0, pf0);           // tile k+2 regs -> LDS
        if (k + 4 < NT) issue_loads(pf0, k + 4);
    }
}

extern "C" void kernel_launch(void* const* d_in, const int* in_sizes, int n_in,
                              void* d_out, int out_size, void* d_ws, size_t ws_size,
                              hipStream_t stream) {
    const float* x    = (const float*)d_in[0];  // (B, C, T) fp32
    const float* beta = (const float*)d_in[1];  // scalar
    const float* vth  = (const float*)d_in[2];  // (C,) fp32
    float* out = (float*)d_out;                 // (B, C, T) fp32

    dim3 grid(LIF_BC / ROWS);                   // 1024 one-wave blocks
    lif_fwd<<<grid, 64, 0, stream>>>(x, beta, vth, out);
}